// Round 6
// baseline (463.303 us; speedup 1.0000x reference)
//
#include <hip/hip_runtime.h>
#include <hip/hip_bf16.h>
#include <math.h>

#define NUM_ITEMS 50000
#define NUM_USERS 16384
#define ITEM_BINS 65536   // padded bin count for the item scan
#define H0 512
#define LAT 256
#define FP8_SCALE 64.0f   // weights ~±0.011 are subnormal in e4m3; x64 -> ~0.7 (3% rel err)
#define FP8_INV (1.0f / 64.0f)
#define EPITCH 264        // bf16 pitch of enc LDS tile (16B-aligned, 33*16B rows)

typedef __attribute__((ext_vector_type(8))) short short8;
typedef __attribute__((ext_vector_type(4))) float floatx4;
typedef __attribute__((ext_vector_type(2))) float vf2;

__device__ __forceinline__ unsigned short f2bf(float f) {
    union { float f; unsigned i; } u; u.f = f;
    unsigned r = u.i + 0x7fff + ((u.i >> 16) & 1);   // RNE
    return (unsigned short)(r >> 16);
}
__device__ __forceinline__ float bfhi(unsigned v) {
    union { unsigned i; float f; } u; u.i = v & 0xffff0000u; return u.f;
}
__device__ __forceinline__ float bflo(unsigned v) {
    union { unsigned i; float f; } u; u.i = v << 16; return u.f;
}
__device__ __forceinline__ uint4 pack8(const float* v) {
    uint4 p;
    p.x = (unsigned)f2bf(v[0]) | ((unsigned)f2bf(v[1]) << 16);
    p.y = (unsigned)f2bf(v[2]) | ((unsigned)f2bf(v[3]) << 16);
    p.z = (unsigned)f2bf(v[4]) | ((unsigned)f2bf(v[5]) << 16);
    p.w = (unsigned)f2bf(v[6]) | ((unsigned)f2bf(v[7]) << 16);
    return p;
}
__device__ __forceinline__ unsigned pkfp8_4(float a, float b, float c, float d) {
    int v = __builtin_amdgcn_cvt_pk_fp8_f32(a, b, 0, false);
    v = __builtin_amdgcn_cvt_pk_fp8_f32(c, d, v, true);
    return (unsigned)v;
}
__device__ __forceinline__ void fp8x4_to_f32(unsigned v, float* o) {
    vf2 lo = __builtin_amdgcn_cvt_pk_f32_fp8((int)v, false);
    vf2 hi = __builtin_amdgcn_cvt_pk_f32_fp8((int)v, true);
    o[0] = lo.x; o[1] = lo.y; o[2] = hi.x; o[3] = hi.y;
}

// ================= count + zero loss slot =================
__global__ __launch_bounds__(256) void count_kernel(const int* __restrict__ user, int* __restrict__ cntU,
                                                    const int* __restrict__ t_item, int* __restrict__ cntI,
                                                    float* __restrict__ loss, int n, int nt) {
    if (blockIdx.x == 0 && threadIdx.x == 0) loss[0] = 0.f;
    int i = (blockIdx.x * blockDim.x + threadIdx.x) * 4;
    if (i + 3 < n) {
        int4 u = *(const int4*)(user + i);
        atomicAdd(&cntU[u.x], 1); atomicAdd(&cntU[u.y], 1);
        atomicAdd(&cntU[u.z], 1); atomicAdd(&cntU[u.w], 1);
    } else {
        for (int k = i; k < n; ++k) atomicAdd(&cntU[user[k]], 1);
    }
    if (i + 3 < nt) {
        int4 t = *(const int4*)(t_item + i);
        atomicAdd(&cntI[t.x], 1); atomicAdd(&cntI[t.y], 1);
        atomicAdd(&cntI[t.z], 1); atomicAdd(&cntI[t.w], 1);
    } else {
        for (int k = i; k < nt; ++k) atomicAdd(&cntI[t_item[k]], 1);
    }
}

// ================= dual exclusive scan =================
__device__ void scan_block(const int* __restrict__ cnt, int* __restrict__ offs,
                           int* __restrict__ cursor, int per) {
    __shared__ int ssum[1024];
    int t = threadIdx.x;
    int base = t * per;
    int s = 0;
    for (int j = 0; j < per; j += 4) {
        int4 v = *(const int4*)(cnt + base + j);
        s += v.x + v.y + v.z + v.w;
    }
    ssum[t] = s;
    __syncthreads();
    for (int off = 1; off < 1024; off <<= 1) {
        int v = (t >= off) ? ssum[t - off] : 0;
        __syncthreads();
        ssum[t] += v;
        __syncthreads();
    }
    int run = (t == 0) ? 0 : ssum[t - 1];
    for (int j = 0; j < per; j += 4) {
        int4 v = *(const int4*)(cnt + base + j);
        int4 o;
        o.x = run; run += v.x;
        o.y = run; run += v.y;
        o.z = run; run += v.z;
        o.w = run; run += v.w;
        *(int4*)(offs + base + j) = o;
        *(int4*)(cursor + base + j) = o;
    }
}

__global__ void scan_kernel(const int* __restrict__ cntU, int* __restrict__ offsU, int* __restrict__ curU,
                            const int* __restrict__ cntI, int* __restrict__ offsI, int* __restrict__ curI) {
    if (blockIdx.x == 0) scan_block(cntU, offsU, curU, NUM_USERS / 1024);
    else scan_block(cntI, offsI, curI, ITEM_BINS / 1024);
}

// ================= mega: scatter | register-transpose W_enc->fp8 | W_dec->fp8 | W1/W2->bf16 =================
// No LDS anywhere -> occupancy is VGPR-bound; all global accesses lane-coalesced.
__global__ __launch_bounds__(256) void mega_kernel(
        const int* __restrict__ user, const int* __restrict__ item,
        const float* __restrict__ rating, int* __restrict__ curU, int2* __restrict__ s_pack,
        const int* __restrict__ t_user, const int* __restrict__ t_item,
        const float* __restrict__ t_rating, int* __restrict__ curI, int4* __restrict__ st_pack,
        const float* __restrict__ W_enc, unsigned char* __restrict__ wtb8,
        const float* __restrict__ W_dec, unsigned char* __restrict__ wdb8,
        const float* __restrict__ W1, unsigned short* __restrict__ w1b,
        const float* __restrict__ W2, unsigned short* __restrict__ w2b,
        int n, int nt, int SB, int TB, int DB) {
    int bid = blockIdx.x;
    int tid = threadIdx.x;
    int wid = tid >> 6, lane = tid & 63;
    if (bid < SB) {
        // ---- scatter: interactions by user (int2), targets by item (int4) ----
        int i = bid * 256 + tid;
        if (i < n) {
            int u = user[i];
            int pos = atomicAdd(&curU[u], 1);
            s_pack[pos] = make_int2(item[i], __float_as_int(rating[i]));
        }
        if (i < nt) {
            int it = t_item[i];
            int pos = atomicAdd(&curI[it], 1);
            st_pack[pos] = make_int4(t_user[i], it, __float_as_int(t_rating[i]), i);
        }
    } else if (bid < SB + TB) {
        // ---- register transpose: block = 64 items x 64 h; wave w owns h-block of 16 ----
        const int TBX = (NUM_ITEMS + 63) / 64;   // 782
        int b = bid - SB;
        int x0 = (b % TBX) * 64;
        int y0 = (b / TBX) * 64;
        int h0 = y0 + wid * 16;
        int it = x0 + lane;
        if (it < NUM_ITEMS) {
            float v[16];
#pragma unroll
            for (int e = 0; e < 16; ++e)
                v[e] = W_enc[(size_t)(h0 + e) * NUM_ITEMS + it];   // 64 lanes coalesced
            uint4 o;
            o.x = pkfp8_4(v[0] * FP8_SCALE, v[1] * FP8_SCALE, v[2] * FP8_SCALE, v[3] * FP8_SCALE);
            o.y = pkfp8_4(v[4] * FP8_SCALE, v[5] * FP8_SCALE, v[6] * FP8_SCALE, v[7] * FP8_SCALE);
            o.z = pkfp8_4(v[8] * FP8_SCALE, v[9] * FP8_SCALE, v[10] * FP8_SCALE, v[11] * FP8_SCALE);
            o.w = pkfp8_4(v[12] * FP8_SCALE, v[13] * FP8_SCALE, v[14] * FP8_SCALE, v[15] * FP8_SCALE);
            *(uint4*)(wtb8 + (size_t)it * H0 + h0) = o;
        }
    } else if (bid < SB + TB + DB) {
        // ---- W_dec f32 -> fp8 (x64): lane-interleaved float4 loads, dword stores ----
        size_t base = (size_t)(bid - SB - TB) * 4096 + wid * 1024 + lane * 4;
#pragma unroll
        for (int c = 0; c < 4; ++c) {
            float4 v = *(const float4*)(W_dec + base + c * 256);
            *(unsigned*)(wdb8 + base + c * 256) =
                pkfp8_4(v.x * FP8_SCALE, v.y * FP8_SCALE, v.z * FP8_SCALE, v.w * FP8_SCALE);
        }
    } else {
        // ---- W1 / W2 cast to bf16, 32 blocks each ----
        int b2i = bid - SB - TB - DB;
        const float* src = (b2i < 32) ? W1 : W2;
        unsigned short* dst = (b2i < 32) ? w1b : w2b;
        size_t base = (size_t)(b2i & 31) * 4096 + wid * 1024 + lane * 4;
#pragma unroll
        for (int c = 0; c < 4; ++c) {
            float4 v = *(const float4*)(src + base + c * 256);
            uint2 o;
            o.x = (unsigned)f2bf(v.x) | ((unsigned)f2bf(v.y) << 16);
            o.y = (unsigned)f2bf(v.z) | ((unsigned)f2bf(v.w) << 16);
            *(uint2*)(dst + base + c * 256) = o;
        }
    }
}

// ================= per-user segment sum: one wave per user, 2-deep pipeline =================
__global__ __launch_bounds__(256) void agg_kernel(const unsigned char* __restrict__ wtb8,
                                                  const int* __restrict__ offs,
                                                  const int* __restrict__ ends,
                                                  const int2* __restrict__ s_pack,
                                                  const float* __restrict__ b_enc,
                                                  unsigned short* __restrict__ xb) {
    int wid = threadIdx.x >> 6, lane = threadIdx.x & 63;
    int u = blockIdx.x * 4 + wid;
    int j0 = offs[u], j1 = ends[u];
    float acc[8] = {};
    int j = j0;
    for (; j + 1 < j1; j += 2) {
        int2 a = s_pack[j];
        int2 b = s_pack[j + 1];
        uint2 va = ((const uint2*)(wtb8 + (size_t)a.x * H0))[lane];
        uint2 vb = ((const uint2*)(wtb8 + (size_t)b.x * H0))[lane];
        float ra = __int_as_float(a.y), rb = __int_as_float(b.y);
        float wa[8], wb[8];
        fp8x4_to_f32(va.x, wa); fp8x4_to_f32(va.y, wa + 4);
        fp8x4_to_f32(vb.x, wb); fp8x4_to_f32(vb.y, wb + 4);
#pragma unroll
        for (int e = 0; e < 8; ++e) acc[e] += wa[e] * ra + wb[e] * rb;
    }
    if (j < j1) {
        int2 a = s_pack[j];
        uint2 va = ((const uint2*)(wtb8 + (size_t)a.x * H0))[lane];
        float ra = __int_as_float(a.y);
        float wa[8];
        fp8x4_to_f32(va.x, wa); fp8x4_to_f32(va.y, wa + 4);
#pragma unroll
        for (int e = 0; e < 8; ++e) acc[e] += wa[e] * ra;
    }
    float4 b0 = ((const float4*)b_enc)[lane * 2];
    float4 b1 = ((const float4*)b_enc)[lane * 2 + 1];
    float o[8];
    o[0] = tanhf(acc[0] * FP8_INV + b0.x); o[1] = tanhf(acc[1] * FP8_INV + b0.y);
    o[2] = tanhf(acc[2] * FP8_INV + b0.z); o[3] = tanhf(acc[3] * FP8_INV + b0.w);
    o[4] = tanhf(acc[4] * FP8_INV + b1.x); o[5] = tanhf(acc[5] * FP8_INV + b1.y);
    o[6] = tanhf(acc[6] * FP8_INV + b1.z); o[7] = tanhf(acc[7] * FP8_INV + b1.w);
    ((uint4*)(xb + (size_t)u * H0))[lane] = pack8(o);
}

// ================= fused MLP: dec = tanh(tanh(x@W1^T+b1)@W2^T+b2), block = 64 users =================
__global__ __launch_bounds__(256) void mlp_kernel(const unsigned short* __restrict__ xb,
                                                  const unsigned short* __restrict__ w1b,
                                                  const float* __restrict__ b1,
                                                  const unsigned short* __restrict__ w2b,
                                                  const float* __restrict__ b2,
                                                  unsigned short* __restrict__ dec_b) {
    __shared__ unsigned short Ash[64 * 32];        // 4 KB  (phase-1 A staging)
    __shared__ unsigned short Bsh[512 * 32];       // 32 KB (phase-1 uses 16 KB, phase-2 all)
    __shared__ unsigned short encs[64 * EPITCH];   // 33 KB (enc tile, bf16)
    int tid = threadIdx.x;
    int wid = tid >> 6, lane = tid & 63;
    int quad = lane >> 4, l16 = lane & 15;
    int m0 = blockIdx.x * 64;
    int srow = lane >> 2;
    int scol = (lane & 3) * 8;

    // ---- phase 1: enc[64][256] = tanh(x @ W1^T + b1), K=512 ----
    {
        floatx4 acc[4][4] = {};
        for (int k0 = 0; k0 < 512; k0 += 32) {
#pragma unroll
            for (int i = 0; i < 5; ++i) {
                int c = wid * 5 + i;   // 0..19 : A chunks 0-3, B chunks 4-19
                if (c < 4) {
                    const unsigned short* ga = xb + (size_t)(m0 + c * 16 + srow) * 512 + k0 + scol;
                    __builtin_amdgcn_global_load_lds(
                        (const __attribute__((address_space(1))) void*)ga,
                        (__attribute__((address_space(3))) void*)((__attribute__((address_space(3))) char*)Ash + c * 1024),
                        16, 0, 0);
                } else {
                    const unsigned short* gb = w1b + (size_t)((c - 4) * 16 + srow) * 512 + k0 + scol;
                    __builtin_amdgcn_global_load_lds(
                        (const __attribute__((address_space(1))) void*)gb,
                        (__attribute__((address_space(3))) void*)((__attribute__((address_space(3))) char*)Bsh + (c - 4) * 1024),
                        16, 0, 0);
                }
            }
            __syncthreads();
            short8 af[4], bfr[4];
#pragma unroll
            for (int i = 0; i < 4; ++i)
                af[i] = ((const short8*)Ash)[(i * 16 + l16) * 4 + quad];
#pragma unroll
            for (int j = 0; j < 4; ++j) {
                int nl = wid * 64 + j * 16 + l16;
                bfr[j] = ((const short8*)Bsh)[nl * 4 + quad];
            }
#pragma unroll
            for (int i = 0; i < 4; ++i)
#pragma unroll
                for (int j = 0; j < 4; ++j)
                    acc[i][j] = __builtin_amdgcn_mfma_f32_16x16x32_bf16(af[i], bfr[j], acc[i][j], 0, 0, 0);
            __syncthreads();
        }
        // enc tile -> LDS (bias + tanh)
#pragma unroll
        for (int j = 0; j < 4; ++j) {
            int col = wid * 64 + j * 16 + l16;
            float bv = b1[col];
#pragma unroll
            for (int i = 0; i < 4; ++i) {
                int row = i * 16 + quad * 4;
#pragma unroll
                for (int r = 0; r < 4; ++r)
                    encs[(row + r) * EPITCH + col] = f2bf(tanhf(acc[i][j][r] + bv));
            }
        }
    }
    __syncthreads();

    // ---- phase 2: dec[64][512] = tanh(enc @ W2^T + b2), K=256 ----
    floatx4 acc2[4][8] = {};
    for (int k0 = 0; k0 < 256; k0 += 32) {
#pragma unroll
        for (int i = 0; i < 8; ++i) {
            int c = wid * 8 + i;   // 0..31 B chunks (512 rows)
            const unsigned short* gb = w2b + (size_t)(c * 16 + srow) * 256 + k0 + scol;
            __builtin_amdgcn_global_load_lds(
                (const __attribute__((address_space(1))) void*)gb,
                (__attribute__((address_space(3))) void*)((__attribute__((address_space(3))) char*)Bsh + c * 1024),
                16, 0, 0);
        }
        __syncthreads();
        short8 af[4], bfr[8];
#pragma unroll
        for (int i = 0; i < 4; ++i)
            af[i] = *(const short8*)(encs + (size_t)(i * 16 + l16) * EPITCH + k0 + quad * 8);
#pragma unroll
        for (int j = 0; j < 8; ++j) {
            int nl = wid * 128 + j * 16 + l16;
            bfr[j] = ((const short8*)Bsh)[nl * 4 + quad];
        }
#pragma unroll
        for (int i = 0; i < 4; ++i)
#pragma unroll
            for (int j = 0; j < 8; ++j)
                acc2[i][j] = __builtin_amdgcn_mfma_f32_16x16x32_bf16(af[i], bfr[j], acc2[i][j], 0, 0, 0);
        __syncthreads();
    }
#pragma unroll
    for (int j = 0; j < 8; ++j) {
        int col = wid * 128 + j * 16 + l16;
        float bv = b2[col];
#pragma unroll
        for (int i = 0; i < 4; ++i) {
            int row = m0 + i * 16 + quad * 4;
#pragma unroll
            for (int r = 0; r < 4; ++r)
                dec_b[(size_t)(row + r) * 512 + col] = f2bf(tanhf(acc2[i][j][r] + bv));
        }
    }
}

// ================= predict over item-sorted packed targets =================
__global__ __launch_bounds__(256) void predict_kernel(const unsigned short* __restrict__ dec_b,
                                                      const unsigned char* __restrict__ wdb8,
                                                      const float* __restrict__ b_dec,
                                                      const int4* __restrict__ st,
                                                      float* __restrict__ pred,
                                                      float* __restrict__ partials, int NT) {
    __shared__ float wsum[4];
    int wid = threadIdx.x >> 6, lane = threadIdx.x & 63;
    int base = (blockIdx.x * 4 + wid) * 4;
    float sq = 0.f;
    int4 tv[4];
    uint4 gv[4];
    uint2 wv[4];
#pragma unroll
    for (int t = 0; t < 4; ++t) tv[t] = st[min(base + t, NT - 1)];
#pragma unroll
    for (int t = 0; t < 4; ++t) {
        gv[t] = ((const uint4*)(dec_b + (size_t)tv[t].x * H0))[lane];
        wv[t] = ((const uint2*)(wdb8 + (size_t)tv[t].y * H0))[lane];
    }
#pragma unroll
    for (int t = 0; t < 4; ++t) {
        float wf[8];
        fp8x4_to_f32(wv[t].x, wf);
        fp8x4_to_f32(wv[t].y, wf + 4);
        float s = bflo(gv[t].x) * wf[0] + bfhi(gv[t].x) * wf[1]
                + bflo(gv[t].y) * wf[2] + bfhi(gv[t].y) * wf[3]
                + bflo(gv[t].z) * wf[4] + bfhi(gv[t].z) * wf[5]
                + bflo(gv[t].w) * wf[6] + bfhi(gv[t].w) * wf[7];
#pragma unroll
        for (int off = 32; off; off >>= 1) s += __shfl_xor(s, off, 64);
        if (lane == 0 && base + t < NT) {
            float p = s * FP8_INV + b_dec[tv[t].y];
            pred[tv[t].w] = p;
            float d = p - __int_as_float(tv[t].z);
            sq += d * d;
        }
    }
    if (lane == 0) wsum[wid] = sq;
    __syncthreads();
    if (threadIdx.x == 0) partials[blockIdx.x] = wsum[0] + wsum[1] + wsum[2] + wsum[3];
}

__global__ void loss_reduce(const float* __restrict__ partials, float* __restrict__ out_loss,
                            int nPart, float invNT) {
    __shared__ float s[256];
    int t = threadIdx.x;
    float a = 0.f;
    const float4* p4 = (const float4*)partials;
    int n4 = nPart >> 2;
    for (int i = t; i < n4; i += 256) {
        float4 v = p4[i];
        a += v.x + v.y + v.z + v.w;
    }
    for (int i = (n4 << 2) + t; i < nPart; i += 256) a += partials[i];
    s[t] = a;
    __syncthreads();
    for (int off = 128; off; off >>= 1) {
        if (t < off) s[t] += s[t + off];
        __syncthreads();
    }
    if (t == 0) out_loss[0] = s[0] * invNT;
}

extern "C" void kernel_launch(void* const* d_in, const int* in_sizes, int n_in,
                              void* d_out, int out_size, void* d_ws, size_t ws_size,
                              hipStream_t stream) {
    const int* user = (const int*)d_in[0];
    const int* item = (const int*)d_in[1];
    const float* rating = (const float*)d_in[2];
    const int* t_user = (const int*)d_in[3];
    const int* t_item = (const int*)d_in[4];
    const float* t_rating = (const float*)d_in[5];
    const float* W_enc = (const float*)d_in[6];
    const float* b_enc = (const float*)d_in[7];
    const float* W1 = (const float*)d_in[8];
    const float* b1 = (const float*)d_in[9];
    const float* W2 = (const float*)d_in[10];
    const float* b2 = (const float*)d_in[11];
    const float* W_dec = (const float*)d_in[12];
    const float* b_dec = (const float*)d_in[13];
    const int N = in_sizes[0];
    const int NT = in_sizes[3];

    char* ws = (char*)d_ws;
    size_t off = 0;
    auto alloc = [&](size_t bytes) {
        void* p = ws + off;
        off = (off + bytes + 255) & ~(size_t)255;
        return p;
    };
    unsigned char* wtb8 = (unsigned char*)alloc((size_t)NUM_ITEMS * H0);        // 25.6 MB
    unsigned char* wdb8 = (unsigned char*)alloc((size_t)NUM_ITEMS * H0);        // 25.6 MB
    unsigned short* xb = (unsigned short*)alloc((size_t)NUM_USERS * H0 * 2);    // 16 MB
    unsigned short* dec_b = (unsigned short*)alloc((size_t)NUM_USERS * H0 * 2); // 16 MB
    unsigned short* w1b = (unsigned short*)alloc((size_t)LAT * H0 * 2);
    unsigned short* w2b = (unsigned short*)alloc((size_t)H0 * LAT * 2);
    int* cntU = (int*)alloc((size_t)(NUM_USERS + ITEM_BINS) * 4);
    int* cntI = cntU + NUM_USERS;
    int* offsU = (int*)alloc((size_t)NUM_USERS * 4);
    int* curU = (int*)alloc((size_t)NUM_USERS * 4);
    int* offsI = (int*)alloc((size_t)ITEM_BINS * 4);
    int* curI = (int*)alloc((size_t)ITEM_BINS * 4);
    int2* s_pack = (int2*)alloc((size_t)N * 8);
    int4* st_pack = (int4*)alloc((size_t)NT * 16);
    const int predBlocks = (NT + 15) / 16;
    float* partials = (float*)alloc((size_t)predBlocks * 4);

    float* pred = (float*)d_out;
    float* loss = pred + NT;

    const int maxNNT = N > NT ? N : NT;
    const int SB = (maxNNT + 255) / 256;                 // 1024 scatter blocks
    const int TBX = (NUM_ITEMS + 63) / 64;               // 782
    const int TB = TBX * (H0 / 64);                      // 6256 transpose blocks
    const int DB = (NUM_ITEMS * H0) / 4096;              // 6250 W_dec cast blocks
    const int WB = 64;                                   // W1+W2 cast blocks

    hipMemsetAsync(cntU, 0, (size_t)(NUM_USERS + ITEM_BINS) * 4, stream);
    count_kernel<<<(maxNNT + 1023) / 1024, 256, 0, stream>>>(user, cntU, t_item, cntI, loss, N, NT);
    scan_kernel<<<2, 1024, 0, stream>>>(cntU, offsU, curU, cntI, offsI, curI);
    mega_kernel<<<SB + TB + DB + WB, 256, 0, stream>>>(
        user, item, rating, curU, s_pack,
        t_user, t_item, t_rating, curI, st_pack,
        W_enc, wtb8, W_dec, wdb8, W1, w1b, W2, w2b,
        N, NT, SB, TB, DB);
    agg_kernel<<<NUM_USERS / 4, 256, 0, stream>>>(wtb8, offsU, curU, s_pack, b_enc, xb);
    mlp_kernel<<<NUM_USERS / 64, 256, 0, stream>>>(xb, w1b, b1, w2b, b2, dec_b);
    predict_kernel<<<predBlocks, 256, 0, stream>>>(dec_b, wdb8, b_dec, st_pack, pred, partials, NT);
    loss_reduce<<<1, 256, 0, stream>>>(partials, loss, predBlocks, 1.0f / NT);
}